// Round 1
// baseline (452.711 us; speedup 1.0000x reference)
//
#include <hip/hip_runtime.h>

// SelfAttention: B=8, S=2048, D=1024, U=1024, fp32 in/out.
// R5: port the three GEMMs (qkv/scores/pv) from the 2-phase 128^2 structure
// (m97-class, measured MfmaUtil 45%, ~960 TF) to the 256^2 8-phase counted-
// vmcnt schedule (T2+T3+T4+T5): 8 waves (2x4), BK=64, 128 KiB LDS (2 dbuf x
// {A,B} x 2 halves x 128x64 fp16), one half-tile staged per phase, stream 6
// phases ahead, ONE s_waitcnt vmcnt(8) per K-tile (vmcnt(0) only at last
// tile), raw s_barrier pairs per phase, setprio(1) around MFMA clusters.
// Staging keeps the R2-verified XOR swizzle (slot (row,c8) holds global
// colgroup c8^(row&7)) per 128x64 half-tile -> 0 bank conflicts.
//
// Hazard ledger (phases are [reads | stage-issue | bar1 | lgkm | MFMA | bar2]):
//  - tile t's half-tiles staged at (t-2,1)=B0 (t-2,2)=B1 (t-2,3)=A1 (t-1,0)=A0;
//    all are >= 5th-newest at (t,0)'s vmcnt(8) -> forced complete, then bar1
//    publishes cross-wave. Tile t+1's 4 half-tiles stay in flight.
//  - B frags are register-cached in phase 0 (reads drained before bar2(t,0));
//    stage B0(t+2)@(t,1), B1(t+2)@(t,2) into the same-parity buffer touch B
//    regions only after that -> no WAR. A-quarters q0,q1,{q2,q3} read in
//    phases 0,1,2 (drained before bar2(t,2)); stage A1(t+2)@(t,3) safe.
//    A0(t+1)@(t,0) writes the other-parity buffer (tile t-1 long drained).
// Workspace: 33.6(Xh) + 6.3(WbT) + 33.6*3(QKV) + 67.1(P) = 207.7 MB

typedef _Float16 half8  __attribute__((ext_vector_type(8)));
typedef _Float16 half4v __attribute__((ext_vector_type(4)));
typedef _Float16 half2v __attribute__((ext_vector_type(2)));
typedef float    floatx4 __attribute__((ext_vector_type(4)));

// ---- async stage: one 128x64 fp16 half-tile (16 KB) -> LDS, swizzled ----
// 2 global_load_lds_dwordx4 per thread (512 threads x 2 x 16B = 16 KB).
__device__ __forceinline__ void stage_ht(const _Float16* __restrict__ src, int ld,
                                         _Float16* __restrict__ dst, int wave, int lane) {
#pragma unroll
    for (int i = 0; i < 2; ++i) {
        int q = wave * 2 + i;            // 16 wave-chunks of 1 KB
        int c = q * 64 + lane;           // 8-elem chunk id in [0,1024)
        int row = c >> 3, c8 = c & 7;
        int cg = c8 ^ (row & 7);         // pre-swizzled global source colgroup
        __builtin_amdgcn_global_load_lds(
            (const __attribute__((address_space(1))) unsigned int*)(src + (size_t)row * ld + cg * 8),
            (__attribute__((address_space(3))) unsigned int*)(dst + q * 512),
            16, 0, 0);
    }
}

// pk-add sum of 8 halves -> float
__device__ __forceinline__ float sum8h(half8 a) {
    union { half8 v; half2v h2[4]; } u; u.v = a;
    half2v s0 = u.h2[0] + u.h2[1];
    half2v s1 = u.h2[2] + u.h2[3];
    half2v s  = s0 + s1;
    return (float)s[0] + (float)s[1];
}

#define SA_(T, h) stage_ht(A + (size_t)((h) * 128) * lda + (size_t)(T) * 64, lda, \
                           ShA + (((T) & 1) * 2 + (h)) * 8192, wave, lane)
#define SB_(T, h) stage_ht(B + (size_t)((h) * 128) * ldb + (size_t)(T) * 64, ldb, \
                           ShB + (((T) & 1) * 2 + (h)) * 8192, wave, lane)

#define LOADA(aq, i0)                                                        \
    _Pragma("unroll")                                                        \
    for (int ii = 0; ii < 2; ++ii) {                                         \
        int rr = ((i0) + ii) * 16 + l15;                                     \
        _Pragma("unroll")                                                    \
        for (int kk = 0; kk < 2; ++kk) {                                     \
            int cg = (kk * 4 + q4) ^ (rr & 7);                               \
            aq[ii][kk] = *(const half8*)(As + rr * 64 + cg * 8);             \
            if (RSUM) rsum[(i0) + ii] += sum8h(aq[ii][kk]);                  \
        }                                                                    \
    }

#define MFMAQ(aq, i0)                                                        \
    asm volatile("s_waitcnt lgkmcnt(0)" ::: "memory");                       \
    __builtin_amdgcn_s_setprio(1);                                           \
    _Pragma("unroll")                                                        \
    for (int kk = 0; kk < 2; ++kk)                                           \
        _Pragma("unroll")                                                    \
        for (int ii = 0; ii < 2; ++ii)                                       \
            _Pragma("unroll")                                                \
            for (int j = 0; j < 4; ++j)                                      \
                acc[(i0) + ii][j] = __builtin_amdgcn_mfma_f32_16x16x32_f16(  \
                    aq[ii][kk], b[j][kk], acc[(i0) + ii][j], 0, 0, 0);       \
    __builtin_amdgcn_s_setprio(0);

#define BARF() do { __builtin_amdgcn_s_barrier(); asm volatile("" ::: "memory"); } while (0)

// ---- shared 256x256-tile 8-phase GEMM main loop ----
// A: 256 rows (caller pre-offset by m0) x K, row-major ld=lda
// B: 256 rows (caller pre-offset by n0) x K, row-major ld=ldb
template<bool RSUM>
__device__ __forceinline__ void gemm8p(const _Float16* __restrict__ A, int lda,
                                       const _Float16* __restrict__ B, int ldb,
                                       int K, _Float16* __restrict__ ShA,
                                       _Float16* __restrict__ ShB,
                                       int wave, int lane,
                                       floatx4 (&acc)[8][4], float (&rsum)[8]) {
    const int wm = wave >> 2, wn = wave & 3;
    const int l15 = lane & 15, q4 = lane >> 4;
    const int NT = K >> 6;

    // prologue stream: B0(0),B1(0),A1(0),A0(0),B0(1),B1(1),A1(1)
    SB_(0, 0); SB_(0, 1); SA_(0, 1); SA_(0, 0);
    if (NT > 1) { SB_(1, 0); SB_(1, 1); SA_(1, 1); }

    for (int t = 0; t < NT; ++t) {
        const _Float16* As = ShA + (t & 1) * 16384 + wm * 8192;
        const _Float16* Bs = ShB + (t & 1) * 16384 + (wn >> 1) * 8192;
        const int rb = (wn & 1) * 64;
        half8 b[4][2];
        half8 a0[2][2], a1[2][2], a2[2][2], a3[2][2];

        // ---- phase 0: force tile t, read B(all)+A q0, MFMA q0 ----
        if (t + 1 < NT) SA_(t + 1, 0);
        if (t == NT - 1) asm volatile("s_waitcnt vmcnt(0)" ::: "memory");
        else             asm volatile("s_waitcnt vmcnt(8)" ::: "memory");
        BARF();
#pragma unroll
        for (int j = 0; j < 4; ++j) {
            int rr = rb + j * 16 + l15;
#pragma unroll
            for (int kk = 0; kk < 2; ++kk) {
                int cg = (kk * 4 + q4) ^ (rr & 7);
                b[j][kk] = *(const half8*)(Bs + rr * 64 + cg * 8);
            }
        }
        LOADA(a0, 0);
        MFMAQ(a0, 0);
        BARF();

        // ---- phase 1: read A q1, stage B0(t+2), MFMA q1 ----
        LOADA(a1, 2);
        if (t + 2 < NT) SB_(t + 2, 0);
        BARF();
        MFMAQ(a1, 2);
        BARF();

        // ---- phase 2: read A q2+q3, stage B1(t+2), MFMA q2 ----
        LOADA(a2, 4);
        LOADA(a3, 6);
        if (t + 2 < NT) SB_(t + 2, 1);
        BARF();
        MFMAQ(a2, 4);
        BARF();

        // ---- phase 3: stage A1(t+2), MFMA q3 (from regs) ----
        if (t + 2 < NT) SA_(t + 2, 1);
        BARF();
        MFMAQ(a3, 6);
        BARF();
    }
}

// ---- kernel 0: cast X fp32 -> fp16 ----
__global__ void cast_x(const float* __restrict__ X, _Float16* __restrict__ Xh) {
    size_t i = ((size_t)blockIdx.x * 256 + threadIdx.x) * 8;
    float4 v0 = *(const float4*)(X + i);
    float4 v1 = *(const float4*)(X + i + 4);
    half8 hh;
    hh[0] = (_Float16)v0.x; hh[1] = (_Float16)v0.y; hh[2] = (_Float16)v0.z; hh[3] = (_Float16)v0.w;
    hh[4] = (_Float16)v1.x; hh[5] = (_Float16)v1.y; hh[6] = (_Float16)v1.z; hh[7] = (_Float16)v1.w;
    *(half8*)(Xh + i) = hh;
}

// ---- kernel 1: transpose-cast weights to fp16 ----
__global__ void prep_weights(const float* __restrict__ Wq, const float* __restrict__ Wk,
                             const float* __restrict__ Wv, _Float16* __restrict__ WbT) {
    int g = blockIdx.z;
    const float* W = (g == 0) ? Wq : (g == 1) ? Wk : Wv;
    __shared__ float tile[32][33];
    int u0 = blockIdx.x * 32, d0 = blockIdx.y * 32;
    int tx = threadIdx.x & 31, ty = threadIdx.x >> 5;
#pragma unroll
    for (int i = 0; i < 32; i += 8)
        tile[ty + i][tx] = W[(size_t)(d0 + ty + i) * 1024 + (u0 + tx)];
    __syncthreads();
#pragma unroll
    for (int i = 0; i < 32; i += 8)
        WbT[(size_t)g * 1024 * 1024 + (size_t)(u0 + ty + i) * 1024 + (d0 + tx)] =
            (_Float16)tile[tx][ty + i];
}

// ---- kernel 2: fused QKV projection (256^2 tiles, 8-phase) ----
// grid (12,64): blockIdx.x>>2 selects Q/K/V (block-uniform), &3 is the u-tile.
__global__ __launch_bounds__(512, 2)
void qkv_gemm(const _Float16* __restrict__ Xh, const _Float16* __restrict__ WbT,
              _Float16* __restrict__ Qh, _Float16* __restrict__ Kh,
              _Float16* __restrict__ Vt) {
    __shared__ __align__(16) _Float16 ShA[32768];
    __shared__ __align__(16) _Float16 ShB[32768];
    int t = threadIdx.x;
    int lane = t & 63, wave = t >> 6;
    int wm = wave >> 2, wn = wave & 3;
    int l15 = lane & 15, q4 = lane >> 4;
    int which = blockIdx.x >> 2;            // 0=Q 1=K 2=V
    int u0 = (blockIdx.x & 3) * 256;
    int m0 = blockIdx.y * 256;
    const _Float16* A = Xh + (size_t)m0 * 1024;
    const _Float16* B = WbT + (size_t)which * 1024 * 1024 + (size_t)u0 * 1024;
    floatx4 acc[8][4] = {};
    float rsum[8] = {};
    gemm8p<false>(A, 1024, B, 1024, 1024, ShA, ShB, wave, lane, acc, rsum);

    int bz = m0 >> 11;                       // batch (256-row tiles never straddle)
    int sbase = (m0 & 2047) + wm * 128;
    if (which < 2) {
        _Float16* db = (which ? Kh : Qh) + (size_t)bz * 2048 * 1024;
#pragma unroll
        for (int i = 0; i < 8; ++i)
#pragma unroll
            for (int j = 0; j < 4; ++j)
#pragma unroll
                for (int r = 0; r < 4; ++r) {
                    int s = sbase + i * 16 + q4 * 4 + r;
                    int u = u0 + wn * 64 + j * 16 + l15;
                    db[(size_t)s * 1024 + u] = (_Float16)acc[i][j][r];
                }
    } else {
        _Float16* vb = Vt + (size_t)bz * 1024 * 2048;
#pragma unroll
        for (int i = 0; i < 8; ++i)
#pragma unroll
            for (int j = 0; j < 4; ++j) {
                int s = sbase + i * 16 + q4 * 4;          // 4 consecutive s
                int u = u0 + wn * 64 + j * 16 + l15;
                half4v pk;
#pragma unroll
                for (int r = 0; r < 4; ++r) pk[r] = (_Float16)acc[i][j][r];
                *(half4v*)(vb + (size_t)u * 2048 + s) = pk;  // 8B aligned
            }
    }
}

// ---- kernel 3: scores (256^2 tiles, 8-phase), epilogue = exp + store ----
__global__ __launch_bounds__(512, 2)
void scores_gemm(const _Float16* __restrict__ Qh, const _Float16* __restrict__ Kh,
                 _Float16* __restrict__ P) {
    __shared__ __align__(16) _Float16 ShA[32768];
    __shared__ __align__(16) _Float16 ShB[32768];
    int t = threadIdx.x;
    int lane = t & 63, wave = t >> 6;
    int wm = wave >> 2, wn = wave & 3;
    int l15 = lane & 15, q4 = lane >> 4;
    int m0 = blockIdx.y * 256, n0 = blockIdx.x * 256;
    int batch = blockIdx.z;
    const _Float16* A = Qh + (size_t)batch * 2048 * 1024 + (size_t)m0 * 1024;
    const _Float16* B = Kh + (size_t)batch * 2048 * 1024 + (size_t)n0 * 1024;
    floatx4 acc[8][4] = {};
    float rsum[8] = {};
    gemm8p<false>(A, 1024, B, 1024, 1024, ShA, ShB, wave, lane, acc, rsum);

    _Float16* Pb = P + (size_t)batch * 2048 * 2048;
#pragma unroll
    for (int i = 0; i < 8; ++i)
#pragma unroll
        for (int j = 0; j < 4; ++j)
#pragma unroll
            for (int r = 0; r < 4; ++r) {
                int m = m0 + wm * 128 + i * 16 + q4 * 4 + r;
                int n = n0 + wn * 64 + j * 16 + l15;
                Pb[(size_t)m * 2048 + n] = (_Float16)__expf(acc[i][j][r] * 0.03125f);
            }
}

// ---- kernel 4: P @ V (256^2 tiles, 8-phase) with inline rowsum + norm ----
__global__ __launch_bounds__(512, 2)
void pv_gemm(const _Float16* __restrict__ P, const _Float16* __restrict__ Vt,
             float* __restrict__ out) {
    __shared__ __align__(16) _Float16 ShA[32768];
    __shared__ __align__(16) _Float16 ShB[32768];
    int t = threadIdx.x;
    int lane = t & 63, wave = t >> 6;
    int wm = wave >> 2, wn = wave & 3;
    int l15 = lane & 15, q4 = lane >> 4;
    int m0 = blockIdx.y * 256, n0 = blockIdx.x * 256;
    int batch = blockIdx.z;
    const _Float16* A = P + (size_t)batch * 2048 * 2048 + (size_t)m0 * 2048;
    const _Float16* B = Vt + (size_t)batch * 1024 * 2048 + (size_t)n0 * 2048;
    floatx4 acc[8][4] = {};
    float rsum[8] = {};
    gemm8p<true>(A, 2048, B, 2048, 2048, ShA, ShB, wave, lane, acc, rsum);

    // merge the 4 q4 k-slices: lanes sharing l15 hold partials of the same row
    float rsumf[8];
#pragma unroll
    for (int i = 0; i < 8; ++i) {
        float v = rsum[i] + __shfl_xor(rsum[i], 16);
        rsumf[i] = v + __shfl_xor(v, 32);   // full rowsum of row i*16+l15
    }
    float* ob = out + (size_t)batch * 2048 * 1024;
#pragma unroll
    for (int i = 0; i < 8; ++i)
#pragma unroll
        for (int r = 0; r < 4; ++r) {
            int rloc = q4 * 4 + r;                       // C/D row within 16x16
            float inv = 1.0f / __shfl(rsumf[i], rloc);   // lane rloc holds it
            int m = m0 + wm * 128 + i * 16 + rloc;
#pragma unroll
            for (int j = 0; j < 4; ++j) {
                int n = n0 + wn * 64 + j * 16 + l15;
                ob[(size_t)m * 1024 + n] = acc[i][j][r] * inv;
            }
        }
}

extern "C" void kernel_launch(void* const* d_in, const int* in_sizes, int n_in,
                              void* d_out, int out_size, void* d_ws, size_t ws_size,
                              hipStream_t stream) {
    const float* X  = (const float*)d_in[0];
    const float* Wq = (const float*)d_in[1];
    const float* Wk = (const float*)d_in[2];
    const float* Wv = (const float*)d_in[3];
    float* out = (float*)d_out;

    char* ws = (char*)d_ws;
    size_t off = 0;
    _Float16* Xh  = (_Float16*)(ws + off); off += (size_t)8 * 2048 * 1024 * 2;
    _Float16* WbT = (_Float16*)(ws + off); off += (size_t)3 * 1024 * 1024 * 2;
    _Float16* Qh  = (_Float16*)(ws + off); off += (size_t)8 * 2048 * 1024 * 2;
    _Float16* Kh  = (_Float16*)(ws + off); off += (size_t)8 * 2048 * 1024 * 2;
    _Float16* Vt  = (_Float16*)(ws + off); off += (size_t)8 * 1024 * 2048 * 2;
    _Float16* P   = (_Float16*)(ws + off); off += (size_t)8 * 2048 * 2048 * 2;

    cast_x      <<<dim3(8192, 1, 1), 256, 0, stream>>>(X, Xh);
    prep_weights<<<dim3(32, 32, 3), 256, 0, stream>>>(Wq, Wk, Wv, WbT);
    qkv_gemm    <<<dim3(12, 64, 1), 512, 0, stream>>>(Xh, WbT, Qh, Kh, Vt);
    scores_gemm <<<dim3(8, 8, 8),   512, 0, stream>>>(Qh, Kh, P);
    pv_gemm     <<<dim3(4, 8, 8),   512, 0, stream>>>(P, Vt, out);
}

// Round 2
// 390.364 us; speedup vs baseline: 1.1597x; 1.1597x over previous
//
#include <hip/hip_runtime.h>

// SelfAttention: B=8, S=2048, D=1024, U=1024, fp32 in/out.
// R6: fix the R5 8-phase schedule. R5 post-mortem: phase 0 issued 12 ds_reads
// AFTER the publishing barrier then lgkmcnt(0)'d -> 96 b128 reads/CU burst
// (~1150 cyc) with the MFMA pipe idle, every tile; phases were 12/4/8/0
// read-unbalanced. Measured MfmaUtil 28% matches that model exactly.
// Fix: (a) publish tile t at bar2(t-1, phase3) -- vmcnt placed after phase-3
// MFMA -- so EVERY phase's ds_reads issue pre-barrier against data published
// by an earlier barrier (the m201 invariant); (b) decompose MFMAs by K-half:
// phases read 8/4/8/4 b128 and run 16 MFMA each; b-frags live 2 phases.
//
// Hazard ledger (phase = [reads | stage | bar1 | lgkm0 | MFMA (| vmcnt) | bar2]):
//  - A(t+1) staged at (t,0)/(t,1) -> OTHER-parity buffer; its last readers
//    (tile t-1) drained at lgkm0(t-1,3) which precedes bar2(t-1,3). Safe.
//  - B(t+2) staged at (t,3) -> SAME-parity buffer; B(t)'s last reads (kk1,
//    issued (t,2) pre-bar) drain at each wave's lgkm0(t,2) before bar2(t,2);
//    stage issues after bar2(t,2). Safe.
//  - vmcnt(4) at (t,3) [after MFMA, before bar2]: in-flight newest->oldest =
//    B(t+2)x4 | A1(t+1)x2 | A0(t+1)x2 | B(t+1)x4 -> forces exactly tile t+1's
//    8 loads, leaves B(t+2) in flight. t=NT-2: vmcnt(0). t=NT-1: none.
//  - Prologue: B(0),A(0) [8 loads] + B(1) [4 loads]; vmcnt(4) forces tile 0.
// Staging keeps the R2-verified XOR swizzle (slot (row,c8) holds global
// colgroup c8^(row&7)) per 128x64 half-tile -> 0 bank conflicts.
// Workspace: 33.6(Xh) + 6.3(WbT) + 33.6*3(QKV) + 67.1(P) = 207.7 MB

typedef _Float16 half8  __attribute__((ext_vector_type(8)));
typedef _Float16 half4v __attribute__((ext_vector_type(4)));
typedef _Float16 half2v __attribute__((ext_vector_type(2)));
typedef float    floatx4 __attribute__((ext_vector_type(4)));

// ---- async stage: one 128x64 fp16 half-tile (16 KB) -> LDS, swizzled ----
// 2 global_load_lds_dwordx4 per thread (512 threads x 2 x 16B = 16 KB).
__device__ __forceinline__ void stage_ht(const _Float16* __restrict__ src, int ld,
                                         _Float16* __restrict__ dst, int wave, int lane) {
#pragma unroll
    for (int i = 0; i < 2; ++i) {
        int q = wave * 2 + i;            // 16 wave-chunks of 1 KB
        int c = q * 64 + lane;           // 8-elem chunk id in [0,1024)
        int row = c >> 3, c8 = c & 7;
        int cg = c8 ^ (row & 7);         // pre-swizzled global source colgroup
        __builtin_amdgcn_global_load_lds(
            (const __attribute__((address_space(1))) unsigned int*)(src + (size_t)row * ld + cg * 8),
            (__attribute__((address_space(3))) unsigned int*)(dst + q * 512),
            16, 0, 0);
    }
}

// pk-add sum of 8 halves -> float
__device__ __forceinline__ float sum8h(half8 a) {
    union { half8 v; half2v h2[4]; } u; u.v = a;
    half2v s0 = u.h2[0] + u.h2[1];
    half2v s1 = u.h2[2] + u.h2[3];
    half2v s  = s0 + s1;
    return (float)s[0] + (float)s[1];
}

#define BARF() do { __builtin_amdgcn_s_barrier(); asm volatile("" ::: "memory"); } while (0)

#define SA_(T, h) stage_ht(A + (size_t)((h) * 128) * lda + (size_t)(T) * 64, lda, \
                           ShA + (((T) & 1) * 2 + (h)) * 8192, wave, lane)
#define SB_(T, h) stage_ht(B + (size_t)((h) * 128) * ldb + (size_t)(T) * 64, ldb, \
                           ShB + (((T) & 1) * 2 + (h)) * 8192, wave, lane)

// 4 B-fragments for one K-half (kk)
__device__ __forceinline__ void read_b(const _Float16* __restrict__ Bs, int rb,
                                       int l15, int q4, int kk, half8 (&bf)[4]) {
#pragma unroll
    for (int j = 0; j < 4; ++j) {
        int rr = rb + j * 16 + l15;
        int cg = (kk * 4 + q4) ^ (rr & 7);
        bf[j] = *(const half8*)(Bs + rr * 64 + cg * 8);
    }
}

// 4 A-fragments (rows i0..i0+3) for one K-half (kk), optional rowsum
template<bool RSUM>
__device__ __forceinline__ void read_a(const _Float16* __restrict__ As, int i0,
                                       int l15, int q4, int kk, half8 (&af)[4],
                                       float* rsum) {
#pragma unroll
    for (int ii = 0; ii < 4; ++ii) {
        int rr = (i0 + ii) * 16 + l15;
        int cg = (kk * 4 + q4) ^ (rr & 7);
        af[ii] = *(const half8*)(As + rr * 64 + cg * 8);
        if (RSUM) rsum[i0 + ii] += sum8h(af[ii]);
    }
}

// lgkm0-aligned 16-MFMA cluster at prio 1
__device__ __forceinline__ void mfma16(const half8 (&af)[4], const half8 (&bf)[4],
                                       int i0, floatx4 (&acc)[8][4]) {
    asm volatile("s_waitcnt lgkmcnt(0)" ::: "memory");
    __builtin_amdgcn_sched_barrier(0);
    __builtin_amdgcn_s_setprio(1);
#pragma unroll
    for (int ii = 0; ii < 4; ++ii)
#pragma unroll
        for (int j = 0; j < 4; ++j)
            acc[i0 + ii][j] = __builtin_amdgcn_mfma_f32_16x16x32_f16(
                af[ii], bf[j], acc[i0 + ii][j], 0, 0, 0);
    __builtin_amdgcn_s_setprio(0);
}

// ---- shared 256x256-tile GEMM main loop (4 uniform phases per K-tile) ----
// A: 256 rows (caller pre-offset by m0) x K, row-major ld=lda
// B: 256 rows (caller pre-offset by n0) x K, row-major ld=ldb
// Requires K >= 128 (NT >= 2); here K is 1024 or 2048.
template<bool RSUM>
__device__ __forceinline__ void gemm8p(const _Float16* __restrict__ A, int lda,
                                       const _Float16* __restrict__ B, int ldb,
                                       int K, _Float16* __restrict__ ShA,
                                       _Float16* __restrict__ ShB,
                                       int wave, int lane,
                                       floatx4 (&acc)[8][4], float (&rsum)[8]) {
    const int wm = wave >> 2, wn = wave & 3;
    const int l15 = lane & 15, q4 = lane >> 4;
    const int NT = K >> 6;

    // prologue: tile 0 fully + B(1); force tile 0, leave B(1) in flight
    SB_(0, 0); SB_(0, 1); SA_(0, 0); SA_(0, 1);
    SB_(1, 0); SB_(1, 1);
    asm volatile("s_waitcnt vmcnt(4)" ::: "memory");
    BARF();

    for (int t = 0; t < NT; ++t) {
        const _Float16* As = ShA + (t & 1) * 16384 + wm * 8192;
        const _Float16* Bs = ShB + (t & 1) * 16384 + (wn >> 1) * 8192;
        const int rb = (wn & 1) * 64;
        half8 bf[4], af[4];

        // ---- phase 0: reads {B kk0, A i0-3 kk0}, stage A0(t+1) ----
        read_b(Bs, rb, l15, q4, 0, bf);
        read_a<RSUM>(As, 0, l15, q4, 0, af, rsum);
        if (t + 1 < NT) SA_(t + 1, 0);
        BARF();
        mfma16(af, bf, 0, acc);
        BARF();

        // ---- phase 1: reads {A i4-7 kk0}, stage A1(t+1) ----
        read_a<RSUM>(As, 4, l15, q4, 0, af, rsum);
        if (t + 1 < NT) SA_(t + 1, 1);
        BARF();
        mfma16(af, bf, 4, acc);
        BARF();

        // ---- phase 2: reads {B kk1, A i0-3 kk1} ----
        read_b(Bs, rb, l15, q4, 1, bf);
        read_a<RSUM>(As, 0, l15, q4, 1, af, rsum);
        BARF();
        mfma16(af, bf, 0, acc);
        BARF();

        // ---- phase 3: reads {A i4-7 kk1}, stage B0/B1(t+2), vmcnt, publish ----
        read_a<RSUM>(As, 4, l15, q4, 1, af, rsum);
        if (t + 2 < NT) { SB_(t + 2, 0); SB_(t + 2, 1); }
        BARF();
        mfma16(af, bf, 4, acc);
        if (t + 1 < NT) {
            if (t + 2 < NT) asm volatile("s_waitcnt vmcnt(4)" ::: "memory");
            else            asm volatile("s_waitcnt vmcnt(0)" ::: "memory");
        }
        BARF();   // publishes tile t+1 for (t+1, phase 0)'s pre-bar reads
    }
}

// ---- kernel 0: cast X fp32 -> fp16 ----
__global__ void cast_x(const float* __restrict__ X, _Float16* __restrict__ Xh) {
    size_t i = ((size_t)blockIdx.x * 256 + threadIdx.x) * 8;
    float4 v0 = *(const float4*)(X + i);
    float4 v1 = *(const float4*)(X + i + 4);
    half8 hh;
    hh[0] = (_Float16)v0.x; hh[1] = (_Float16)v0.y; hh[2] = (_Float16)v0.z; hh[3] = (_Float16)v0.w;
    hh[4] = (_Float16)v1.x; hh[5] = (_Float16)v1.y; hh[6] = (_Float16)v1.z; hh[7] = (_Float16)v1.w;
    *(half8*)(Xh + i) = hh;
}

// ---- kernel 1: transpose-cast weights to fp16 ----
__global__ void prep_weights(const float* __restrict__ Wq, const float* __restrict__ Wk,
                             const float* __restrict__ Wv, _Float16* __restrict__ WbT) {
    int g = blockIdx.z;
    const float* W = (g == 0) ? Wq : (g == 1) ? Wk : Wv;
    __shared__ float tile[32][33];
    int u0 = blockIdx.x * 32, d0 = blockIdx.y * 32;
    int tx = threadIdx.x & 31, ty = threadIdx.x >> 5;
#pragma unroll
    for (int i = 0; i < 32; i += 8)
        tile[ty + i][tx] = W[(size_t)(d0 + ty + i) * 1024 + (u0 + tx)];
    __syncthreads();
#pragma unroll
    for (int i = 0; i < 32; i += 8)
        WbT[(size_t)g * 1024 * 1024 + (size_t)(u0 + ty + i) * 1024 + (d0 + tx)] =
            (_Float16)tile[tx][ty + i];
}

// ---- kernel 2: fused QKV projection (256^2 tiles) ----
// grid (12,64): blockIdx.x>>2 selects Q/K/V (block-uniform), &3 is the u-tile.
__global__ __launch_bounds__(512, 2)
void qkv_gemm(const _Float16* __restrict__ Xh, const _Float16* __restrict__ WbT,
              _Float16* __restrict__ Qh, _Float16* __restrict__ Kh,
              _Float16* __restrict__ Vt) {
    __shared__ __align__(16) _Float16 ShA[32768];
    __shared__ __align__(16) _Float16 ShB[32768];
    int t = threadIdx.x;
    int lane = t & 63, wave = t >> 6;
    int wm = wave >> 2, wn = wave & 3;
    int l15 = lane & 15, q4 = lane >> 4;
    int which = blockIdx.x >> 2;            // 0=Q 1=K 2=V
    int u0 = (blockIdx.x & 3) * 256;
    int m0 = blockIdx.y * 256;
    const _Float16* A = Xh + (size_t)m0 * 1024;
    const _Float16* B = WbT + (size_t)which * 1024 * 1024 + (size_t)u0 * 1024;
    floatx4 acc[8][4] = {};
    float rsum[8] = {};
    gemm8p<false>(A, 1024, B, 1024, 1024, ShA, ShB, wave, lane, acc, rsum);

    int bz = m0 >> 11;                       // batch (256-row tiles never straddle)
    int sbase = (m0 & 2047) + wm * 128;
    if (which < 2) {
        _Float16* db = (which ? Kh : Qh) + (size_t)bz * 2048 * 1024;
#pragma unroll
        for (int i = 0; i < 8; ++i)
#pragma unroll
            for (int j = 0; j < 4; ++j)
#pragma unroll
                for (int r = 0; r < 4; ++r) {
                    int s = sbase + i * 16 + q4 * 4 + r;
                    int u = u0 + wn * 64 + j * 16 + l15;
                    db[(size_t)s * 1024 + u] = (_Float16)acc[i][j][r];
                }
    } else {
        _Float16* vb = Vt + (size_t)bz * 1024 * 2048;
#pragma unroll
        for (int i = 0; i < 8; ++i)
#pragma unroll
            for (int j = 0; j < 4; ++j) {
                int s = sbase + i * 16 + q4 * 4;          // 4 consecutive s
                int u = u0 + wn * 64 + j * 16 + l15;
                half4v pk;
#pragma unroll
                for (int r = 0; r < 4; ++r) pk[r] = (_Float16)acc[i][j][r];
                *(half4v*)(vb + (size_t)u * 2048 + s) = pk;  // 8B aligned
            }
    }
}

// ---- kernel 3: scores (256^2 tiles), epilogue = exp + store ----
__global__ __launch_bounds__(512, 2)
void scores_gemm(const _Float16* __restrict__ Qh, const _Float16* __restrict__ Kh,
                 _Float16* __restrict__ P) {
    __shared__ __align__(16) _Float16 ShA[32768];
    __shared__ __align__(16) _Float16 ShB[32768];
    int t = threadIdx.x;
    int lane = t & 63, wave = t >> 6;
    int wm = wave >> 2, wn = wave & 3;
    int l15 = lane & 15, q4 = lane >> 4;
    int m0 = blockIdx.y * 256, n0 = blockIdx.x * 256;
    int batch = blockIdx.z;
    const _Float16* A = Qh + (size_t)batch * 2048 * 1024 + (size_t)m0 * 1024;
    const _Float16* B = Kh + (size_t)batch * 2048 * 1024 + (size_t)n0 * 1024;
    floatx4 acc[8][4] = {};
    float rsum[8] = {};
    gemm8p<false>(A, 1024, B, 1024, 1024, ShA, ShB, wave, lane, acc, rsum);

    _Float16* Pb = P + (size_t)batch * 2048 * 2048;
#pragma unroll
    for (int i = 0; i < 8; ++i)
#pragma unroll
        for (int j = 0; j < 4; ++j)
#pragma unroll
            for (int r = 0; r < 4; ++r) {
                int m = m0 + wm * 128 + i * 16 + q4 * 4 + r;
                int n = n0 + wn * 64 + j * 16 + l15;
                Pb[(size_t)m * 2048 + n] = (_Float16)__expf(acc[i][j][r] * 0.03125f);
            }
}

// ---- kernel 4: P @ V (256^2 tiles) with inline rowsum + normalization ----
__global__ __launch_bounds__(512, 2)
void pv_gemm(const _Float16* __restrict__ P, const _Float16* __restrict__ Vt,
             float* __restrict__ out) {
    __shared__ __align__(16) _Float16 ShA[32768];
    __shared__ __align__(16) _Float16 ShB[32768];
    int t = threadIdx.x;
    int lane = t & 63, wave = t >> 6;
    int wm = wave >> 2, wn = wave & 3;
    int l15 = lane & 15, q4 = lane >> 4;
    int m0 = blockIdx.y * 256, n0 = blockIdx.x * 256;
    int batch = blockIdx.z;
    const _Float16* A = P + (size_t)batch * 2048 * 2048 + (size_t)m0 * 2048;
    const _Float16* B = Vt + (size_t)batch * 1024 * 2048 + (size_t)n0 * 2048;
    floatx4 acc[8][4] = {};
    float rsum[8] = {};
    gemm8p<true>(A, 2048, B, 2048, 2048, ShA, ShB, wave, lane, acc, rsum);

    // merge the 4 q4 k-slices: lanes sharing l15 hold partials of the same row
    float rsumf[8];
#pragma unroll
    for (int i = 0; i < 8; ++i) {
        float v = rsum[i] + __shfl_xor(rsum[i], 16);
        rsumf[i] = v + __shfl_xor(v, 32);   // full rowsum of row i*16+l15
    }
    float* ob = out + (size_t)batch * 2048 * 1024;
#pragma unroll
    for (int i = 0; i < 8; ++i)
#pragma unroll
        for (int r = 0; r < 4; ++r) {
            int rloc = q4 * 4 + r;                       // C/D row within 16x16
            float inv = 1.0f / __shfl(rsumf[i], rloc);   // lane rloc holds it
            int m = m0 + wm * 128 + i * 16 + rloc;
#pragma unroll
            for (int j = 0; j < 4; ++j) {
                int n = n0 + wn * 64 + j * 16 + l15;
                ob[(size_t)m * 1024 + n] = acc[i][j][r] * inv;
            }
        }
}

extern "C" void kernel_launch(void* const* d_in, const int* in_sizes, int n_in,
                              void* d_out, int out_size, void* d_ws, size_t ws_size,
                              hipStream_t stream) {
    const float* X  = (const float*)d_in[0];
    const float* Wq = (const float*)d_in[1];
    const float* Wk = (const float*)d_in[2];
    const float* Wv = (const float*)d_in[3];
    float* out = (float*)d_out;

    char* ws = (char*)d_ws;
    size_t off = 0;
    _Float16* Xh  = (_Float16*)(ws + off); off += (size_t)8 * 2048 * 1024 * 2;
    _Float16* WbT = (_Float16*)(ws + off); off += (size_t)3 * 1024 * 1024 * 2;
    _Float16* Qh  = (_Float16*)(ws + off); off += (size_t)8 * 2048 * 1024 * 2;
    _Float16* Kh  = (_Float16*)(ws + off); off += (size_t)8 * 2048 * 1024 * 2;
    _Float16* Vt  = (_Float16*)(ws + off); off += (size_t)8 * 1024 * 2048 * 2;
    _Float16* P   = (_Float16*)(ws + off); off += (size_t)8 * 2048 * 2048 * 2;

    cast_x      <<<dim3(8192, 1, 1), 256, 0, stream>>>(X, Xh);
    prep_weights<<<dim3(32, 32, 3), 256, 0, stream>>>(Wq, Wk, Wv, WbT);
    qkv_gemm    <<<dim3(12, 64, 1), 512, 0, stream>>>(Xh, WbT, Qh, Kh, Vt);
    scores_gemm <<<dim3(8, 8, 8),   512, 0, stream>>>(Qh, Kh, P);
    pv_gemm     <<<dim3(4, 8, 8),   512, 0, stream>>>(P, Vt, out);
}